// Round 10
// baseline (406.981 us; speedup 1.0000x reference)
//
#include <hip/hip_runtime.h>

#define NN 50000
#define NE 1600000
#define INDIM 256
#define HIDIM 128
#define OUTDIM 64

#define NRANGE 8
#define RSPAN 6250            // NN / NRANGE
#define ACAP 262144           // per-range staging capacity (uint records)
#define NBBLK 1563            // bucket blocks: (NE + 1023) / 1024
#define NWAVE (NBBLK * 4)     // 6252 waves, 256 edges each

typedef unsigned int uint;
typedef unsigned long long ull;
typedef unsigned short ushort;
typedef __attribute__((ext_vector_type(8))) short bf16x8;
typedef __attribute__((ext_vector_type(4))) float f32x4;

__device__ __forceinline__ ushort f2bf(float f) {
    uint u = __float_as_uint(f);
    uint r = (u + 0x7FFFu + ((u >> 16) & 1u)) >> 16;   // RTNE
    return (ushort)r;
}
__device__ __forceinline__ uint pk2(float a, float b) {
    return (uint)f2bf(a) | ((uint)f2bf(b) << 16);
}
__device__ __forceinline__ float bf_lo(uint u) { return __uint_as_float(u << 16); }
__device__ __forceinline__ float bf_hi(uint u) { return __uint_as_float(u & 0xFFFF0000u); }

// ---------------- weight transpose + bf16 convert (fused) ----------------

__global__ void k_wt(const float* __restrict__ W1, const float* __restrict__ W2,
                     ushort* __restrict__ W1T, ushort* __restrict__ W2T) {
    int idx = blockIdx.x * 256 + threadIdx.x;
    if (idx < INDIM * HIDIM) {
        int k = idx / HIDIM, nn = idx % HIDIM;
        W1T[nn * INDIM + k] = f2bf(W1[idx]);
    } else {
        int j = idx - INDIM * HIDIM;
        if (j < HIDIM * OUTDIM) {
            int k = j / OUTDIM, nn = j % OUTDIM;
            W2T[nn * HIDIM + k] = f2bf(W2[j]);
        }
    }
}

// ---------------- bucket phase A1: per-wave range counts (atomic-free) ---------------

__global__ void k_bcount(const int* __restrict__ col, int* __restrict__ wcnt) {
    int tid = threadIdx.x, lane = tid & 63, wid = tid >> 6;
    int gw = blockIdx.x * 4 + wid;
    int base = gw * 256;
    int c[NRANGE] = {};
#pragma unroll
    for (int k = 0; k < 4; k++) {
        int i = base + k * 64 + lane;
        int d = (i < NE) ? col[i] : -1;
        int r = (d >= 0) ? (d / RSPAN) : -1;
#pragma unroll
        for (int rr = 0; rr < NRANGE; rr++)
            c[rr] += __popcll(__ballot(r == rr));
    }
    if (lane == 0) {
#pragma unroll
        for (int rr = 0; rr < NRANGE; rr++)
            wcnt[rr * NWAVE + gw] = c[rr];
    }
}

// ---------------- bucket phase A2: exclusive scan of wave counts per range -----------

__global__ void k_bscan(const int* __restrict__ wcnt, int* __restrict__ wbase,
                        int* __restrict__ rcur) {
    __shared__ int wsum[16];
    __shared__ int woff[16];
    int r = blockIdx.x;
    const int* src = wcnt + r * NWAVE;
    int* dst = wbase + r * NWAVE;
    int tid = threadIdx.x, lane = tid & 63, wid = tid >> 6;
    int seg = tid * 7;                    // 7*1024 = 7168 >= 6252
    int local[7];
    int sum = 0;
#pragma unroll
    for (int j = 0; j < 7; j++) {
        int i = seg + j;
        local[j] = (i < NWAVE) ? src[i] : 0;
        sum += local[j];
    }
    int incl = sum;
#pragma unroll
    for (int off = 1; off < 64; off <<= 1) {
        int t = __shfl_up(incl, off);
        if (lane >= off) incl += t;
    }
    if (lane == 63) wsum[wid] = incl;
    __syncthreads();
    if (wid == 0 && lane < 16) {
        int wv = wsum[lane];
        int wincl = wv;
#pragma unroll
        for (int off = 1; off < 16; off <<= 1) {
            int t = __shfl_up(wincl, off);
            if (lane >= off) wincl += t;
        }
        woff[lane] = wincl - wv;
    }
    __syncthreads();
    int run = incl - sum + woff[wid];
#pragma unroll
    for (int j = 0; j < 7; j++) {
        int i = seg + j;
        if (i < NWAVE) dst[i] = run;
        run += local[j];
    }
    if (tid == 1023) rcur[r] = run;       // range total
}

// ---------------- bucket phase A3: deterministic ballot scatter (atomic-free) --------

__global__ void k_bscatter(const int* __restrict__ row, const int* __restrict__ col,
                           const int* __restrict__ wbase, uint* __restrict__ staged) {
    int tid = threadIdx.x, lane = tid & 63, wid = tid >> 6;
    int gw = blockIdx.x * 4 + wid;
    int base = gw * 256;
    int cur[NRANGE];
#pragma unroll
    for (int rr = 0; rr < NRANGE; rr++) cur[rr] = wbase[rr * NWAVE + gw];
#pragma unroll
    for (int k = 0; k < 4; k++) {
        int i = base + k * 64 + lane;
        int d = -1, s = 0;
        if (i < NE) { d = col[i]; s = row[i]; }
        int r = (d >= 0) ? (d / RSPAN) : -1;
#pragma unroll
        for (int rr = 0; rr < NRANGE; rr++) {
            ull mask = __ballot(r == rr);
            if (mask) {
                if (r == rr) {
                    int prefix = __popcll(mask & ((1ull << lane) - 1ull));
                    staged[(size_t)rr * ACAP + cur[rr] + prefix] =
                        ((uint)s << 13) | (uint)(d - rr * RSPAN);
                }
                cur[rr] += __popcll(mask);
            }
        }
    }
}

// ---------------- k_sort: per-range LDS counting sort -> CSR + row_ptr + dinv --------
// 8 blocks x 1024 threads. Zero global atomics: LDS bins count, in-block scan,
// LDS returning atomics hand out exact CSR slots. Replaces count/scan/place/zero.

__global__ void k_sort(const uint* __restrict__ staged, const int* __restrict__ rcur,
                       int* __restrict__ row_ptr, float* __restrict__ dinv,
                       ushort* __restrict__ ssrc) {
    __shared__ int bins[RSPAN];
    __shared__ int wsum[16];
    __shared__ int woff[16];
    int r = blockIdx.x;
    int tid = threadIdx.x, lane = tid & 63, wid = tid >> 6;
    int lo = r * RSPAN;
    int count = rcur[r];
    int base = 0;
#pragma unroll
    for (int rr = 0; rr < NRANGE; rr++)
        if (rr < r) base += rcur[rr];
    const uint* st = staged + (size_t)r * ACAP;

    for (int i = tid; i < RSPAN; i += 1024) bins[i] = 0;
    __syncthreads();

    // pass 1: count
    for (int i = tid; i < count; i += 1024)
        atomicAdd(&bins[st[i] & 8191u], 1);
    __syncthreads();

    // in-block exclusive scan of bins (7 elems/thread; 7*1024 >= 6250)
    int seg = tid * 7;
    int local[7];
    int sum = 0;
#pragma unroll
    for (int j = 0; j < 7; j++) {
        int i = seg + j;
        local[j] = (i < RSPAN) ? bins[i] : 0;
        sum += local[j];
    }
    int incl = sum;
#pragma unroll
    for (int off = 1; off < 64; off <<= 1) {
        int t = __shfl_up(incl, off);
        if (lane >= off) incl += t;
    }
    if (lane == 63) wsum[wid] = incl;
    __syncthreads();
    if (wid == 0 && lane < 16) {
        int wv = wsum[lane];
        int wincl = wv;
#pragma unroll
        for (int off = 1; off < 16; off <<= 1) {
            int t = __shfl_up(wincl, off);
            if (lane >= off) wincl += t;
        }
        woff[lane] = wincl - wv;
    }
    __syncthreads();
    int run = incl - sum + woff[wid];
#pragma unroll
    for (int j = 0; j < 7; j++) {
        int i = seg + j;
        if (i < RSPAN) {
            row_ptr[lo + i] = base + run;
            dinv[lo + i] = rsqrtf((float)(local[j] + 1));   // +1 self loop
            bins[i] = base + run;     // global cursor for pass 2
        }
        run += local[j];
    }
    if (r == NRANGE - 1 && tid == 1023) row_ptr[NN] = base + count;
    __syncthreads();

    // pass 2: scatter to exact CSR slots via LDS returning atomics
    for (int i = tid; i < count; i += 1024) {
        uint rec = st[i];
        int pos = atomicAdd(&bins[rec & 8191u], 1);
        ssrc[pos] = (ushort)(rec >> 13);
    }
}

// ---------------- GEMM1 (MFMA bf16): x[n][256] @ W1 -> g1s [4][NN][32] bf16 ----------

__global__ void k_gemm1(const float* __restrict__ A, const ushort* __restrict__ W1T,
                        const float* __restrict__ dinv, ushort* __restrict__ g1s, int n) {
    __shared__ ushort As[64 * 40];
    __shared__ ushort Bs[128 * 40];
    int tid = threadIdx.x;
    int w = tid >> 6, lane = tid & 63;
    int ln = lane & 15, quad = lane >> 4;
    int row0 = blockIdx.x * 64;
    int n0 = w * 32;

    f32x4 acc[4][2];
#pragma unroll
    for (int m = 0; m < 4; m++)
#pragma unroll
        for (int t = 0; t < 2; t++) acc[m][t] = (f32x4){0.f, 0.f, 0.f, 0.f};

    int ar = tid >> 2;
    int ac = (tid & 3) * 8;

    for (int k0 = 0; k0 < INDIM; k0 += 32) {
        {   // stage A: 64 rows x 32 k, f32 -> bf16
            int gr = row0 + ar;
            uint4 u = make_uint4(0, 0, 0, 0);
            if (gr < n) {
                const float* p = A + (size_t)gr * INDIM + k0 + ac;
                float4 v0 = *(const float4*)p;
                float4 v1 = *(const float4*)(p + 4);
                u.x = pk2(v0.x, v0.y); u.y = pk2(v0.z, v0.w);
                u.z = pk2(v1.x, v1.y); u.w = pk2(v1.z, v1.w);
            }
            *(uint4*)(As + ar * 40 + ac) = u;
        }
#pragma unroll
        for (int it = 0; it < 2; it++) {   // stage B: 128 rows x 32 k
            int idx = tid + it * 256;
            int bn = idx >> 2, bc = (idx & 3) * 8;
            uint4 u = *(const uint4*)(W1T + (size_t)bn * INDIM + k0 + bc);
            *(uint4*)(Bs + bn * 40 + bc) = u;
        }
        __syncthreads();

        bf16x8 af[4], bf[2];
#pragma unroll
        for (int m = 0; m < 4; m++)
            af[m] = *(const bf16x8*)(As + (m * 16 + ln) * 40 + quad * 8);
#pragma unroll
        for (int t = 0; t < 2; t++)
            bf[t] = *(const bf16x8*)(Bs + (n0 + t * 16 + ln) * 40 + quad * 8);
#pragma unroll
        for (int m = 0; m < 4; m++)
#pragma unroll
            for (int t = 0; t < 2; t++)
                acc[m][t] = __builtin_amdgcn_mfma_f32_16x16x32_bf16(af[m], bf[t], acc[m][t], 0, 0, 0);
        __syncthreads();
    }

#pragma unroll
    for (int m = 0; m < 4; m++) {
#pragma unroll
        for (int r = 0; r < 4; r++) {
            int gr = row0 + m * 16 + quad * 4 + r;
            if (gr < n) {
                float dv = dinv[gr];
#pragma unroll
                for (int t = 0; t < 2; t++) {
                    int cj = t * 16 + ln;
                    g1s[((size_t)w * NN + gr) * 32 + cj] = f2bf(acc[m][t][r] * dv);
                }
            }
        }
    }
}

// ---------------- agg1: hrb[s][d][32] = bf16(relu(dinv[d]*(sum g1[src]+g1[d]) + b1)) -

__global__ void k_agg1(const ushort* __restrict__ g1s, const float* __restrict__ dinv,
                       const int* __restrict__ row_ptr, const ushort* __restrict__ ssrc,
                       const float* __restrict__ b1, ushort* __restrict__ hrb) {
    int slice = blockIdx.x & 3;
    int dbase = (blockIdx.x >> 2) * 32;
    int wid = threadIdx.x >> 6, lane = threadIdx.x & 63;
    int grp = lane >> 3, fl = lane & 7;
    int d = dbase + wid * 8 + grp;
    if (d >= NN) return;
    const ushort* gs = g1s + (size_t)slice * NN * 32 + fl * 4;
    float a0 = 0.f, a1 = 0.f, a2 = 0.f, a3 = 0.f;
    int e0 = row_ptr[d], e1 = row_ptr[d + 1];
    int e = e0;
    for (; e + 1 < e1; e += 2) {
        int s0 = ssrc[e], s1 = ssrc[e + 1];
        uint2 u = *(const uint2*)(gs + (size_t)s0 * 32);
        uint2 v = *(const uint2*)(gs + (size_t)s1 * 32);
        a0 += bf_lo(u.x); a1 += bf_hi(u.x); a2 += bf_lo(u.y); a3 += bf_hi(u.y);
        a0 += bf_lo(v.x); a1 += bf_hi(v.x); a2 += bf_lo(v.y); a3 += bf_hi(v.y);
    }
    if (e < e1) {
        int s0 = ssrc[e];
        uint2 u = *(const uint2*)(gs + (size_t)s0 * 32);
        a0 += bf_lo(u.x); a1 += bf_hi(u.x); a2 += bf_lo(u.y); a3 += bf_hi(u.y);
    }
    uint2 ud = *(const uint2*)(gs + (size_t)d * 32);
    a0 += bf_lo(ud.x); a1 += bf_hi(ud.x); a2 += bf_lo(ud.y); a3 += bf_hi(ud.y);
    float dv = dinv[d];
    float4 bb = *(const float4*)(b1 + slice * 32 + fl * 4);
    ushort4 o;
    o.x = f2bf(fmaxf(a0 * dv + bb.x, 0.f));
    o.y = f2bf(fmaxf(a1 * dv + bb.y, 0.f));
    o.z = f2bf(fmaxf(a2 * dv + bb.z, 0.f));
    o.w = f2bf(fmaxf(a3 * dv + bb.w, 0.f));
    *(ushort4*)(hrb + ((size_t)slice * NN + d) * 32 + fl * 4) = o;
}

// ---------------- GEMM2 (MFMA bf16): hrb [4][NN][32] @ W2 -> g2s [2][NN][32] bf16 ----

__global__ void k_gemm2(const ushort* __restrict__ hrb, const ushort* __restrict__ W2T,
                        const float* __restrict__ dinv, ushort* __restrict__ g2s, int n) {
    __shared__ ushort As[64 * 40];
    __shared__ ushort Bs[64 * 40];
    int tid = threadIdx.x;
    int w = tid >> 6, lane = tid & 63;
    int ln = lane & 15, quad = lane >> 4;
    int row0 = blockIdx.x * 64;
    int n0 = w * 16;

    f32x4 acc[4];
#pragma unroll
    for (int m = 0; m < 4; m++) acc[m] = (f32x4){0.f, 0.f, 0.f, 0.f};

    int ar = tid >> 2;
    int ac = (tid & 3) * 8;

    for (int k0 = 0; k0 < HIDIM; k0 += 32) {
        int hs = k0 >> 5;
        {   // stage A
            int gr = row0 + ar;
            uint4 u = make_uint4(0, 0, 0, 0);
            if (gr < n) u = *(const uint4*)(hrb + ((size_t)hs * NN + gr) * 32 + ac);
            *(uint4*)(As + ar * 40 + ac) = u;
        }
        {   // stage B
            int bn = tid >> 2, bc = (tid & 3) * 8;
            uint4 u = *(const uint4*)(W2T + (size_t)bn * HIDIM + k0 + bc);
            *(uint4*)(Bs + bn * 40 + bc) = u;
        }
        __syncthreads();

        bf16x8 bf = *(const bf16x8*)(Bs + (n0 + ln) * 40 + quad * 8);
#pragma unroll
        for (int m = 0; m < 4; m++) {
            bf16x8 af = *(const bf16x8*)(As + (m * 16 + ln) * 40 + quad * 8);
            acc[m] = __builtin_amdgcn_mfma_f32_16x16x32_bf16(af, bf, acc[m], 0, 0, 0);
        }
        __syncthreads();
    }

    int col = n0 + ln;
    int s2 = col >> 5, cj = col & 31;
#pragma unroll
    for (int m = 0; m < 4; m++) {
#pragma unroll
        for (int r = 0; r < 4; r++) {
            int gr = row0 + m * 16 + quad * 4 + r;
            if (gr < n) {
                g2s[((size_t)s2 * NN + gr) * 32 + cj] = f2bf(acc[m][r] * dinv[gr]);
            }
        }
    }
}

// ---------------- agg2: out[d][64] = dinv[d]*(sum g2[src] + g2[d]) + b2 --------------

__global__ void k_agg2(const ushort* __restrict__ g2s, const float* __restrict__ dinv,
                       const int* __restrict__ row_ptr, const ushort* __restrict__ ssrc,
                       const float* __restrict__ b2, float* __restrict__ out) {
    int slice = blockIdx.x & 1;
    int dbase = (blockIdx.x >> 1) * 32;
    int wid = threadIdx.x >> 6, lane = threadIdx.x & 63;
    int grp = lane >> 3, fl = lane & 7;
    int d = dbase + wid * 8 + grp;
    if (d >= NN) return;
    const ushort* gs = g2s + (size_t)slice * NN * 32 + fl * 4;
    float a0 = 0.f, a1 = 0.f, a2 = 0.f, a3 = 0.f;
    int e0 = row_ptr[d], e1 = row_ptr[d + 1];
    int e = e0;
    for (; e + 1 < e1; e += 2) {
        int s0 = ssrc[e], s1 = ssrc[e + 1];
        uint2 u = *(const uint2*)(gs + (size_t)s0 * 32);
        uint2 v = *(const uint2*)(gs + (size_t)s1 * 32);
        a0 += bf_lo(u.x); a1 += bf_hi(u.x); a2 += bf_lo(u.y); a3 += bf_hi(u.y);
        a0 += bf_lo(v.x); a1 += bf_hi(v.x); a2 += bf_lo(v.y); a3 += bf_hi(v.y);
    }
    if (e < e1) {
        int s0 = ssrc[e];
        uint2 u = *(const uint2*)(gs + (size_t)s0 * 32);
        a0 += bf_lo(u.x); a1 += bf_hi(u.x); a2 += bf_lo(u.y); a3 += bf_hi(u.y);
    }
    uint2 ud = *(const uint2*)(gs + (size_t)d * 32);
    a0 += bf_lo(ud.x); a1 += bf_hi(ud.x); a2 += bf_lo(ud.y); a3 += bf_hi(ud.y);
    float dv = dinv[d];
    float4 bb = *(const float4*)(b2 + slice * 32 + fl * 4);
    float4 r;
    r.x = a0 * dv + bb.x;
    r.y = a1 * dv + bb.y;
    r.z = a2 * dv + bb.z;
    r.w = a3 * dv + bb.w;
    *(float4*)(out + (size_t)d * OUTDIM + slice * 32 + fl * 4) = r;
}

// ---------------- launch ----------------

extern "C" void kernel_launch(void* const* d_in, const int* in_sizes, int n_in,
                              void* d_out, int out_size, void* d_ws, size_t ws_size,
                              hipStream_t stream) {
    const float* x   = (const float*)d_in[0];
    const int*   ei  = (const int*)d_in[1];
    const float* W1  = (const float*)d_in[2];
    const float* b1  = (const float*)d_in[3];
    const float* W2  = (const float*)d_in[4];
    const float* b2  = (const float*)d_in[5];
    float* out = (float*)d_out;

    const int* row = ei;        // sources
    const int* col = ei + NE;   // destinations

    size_t off = 0;
    auto alloc = [&](size_t bytes) {
        void* p = (char*)d_ws + off;
        off += (bytes + 255) & ~(size_t)255;
        return p;
    };
    float*  dinv     = (float*) alloc((size_t)NN * 4);
    int*    row_ptr  = (int*)   alloc((size_t)(NN + 1) * 4);
    int*    rcur     = (int*)   alloc(NRANGE * 4);
    int*    wcnt     = (int*)   alloc((size_t)NRANGE * NWAVE * 4);   // 200 KB
    int*    wbase    = (int*)   alloc((size_t)NRANGE * NWAVE * 4);   // 200 KB
    uint*   staged   = (uint*)  alloc((size_t)NRANGE * ACAP * 4);    // 8 MB
    ushort* ssrc     = (ushort*)alloc((size_t)NE * 2);
    ushort* W1T      = (ushort*)alloc((size_t)INDIM * HIDIM * 2);
    ushort* W2T      = (ushort*)alloc((size_t)HIDIM * OUTDIM * 2);
    ushort* g1s      = (ushort*)alloc((size_t)NN * HIDIM * 2);
    ushort* hrb      = (ushort*)alloc((size_t)NN * HIDIM * 2);
    ushort* g2s      = (ushort*)alloc((size_t)NN * OUTDIM * 2);

    const int nb32 = (NN + 31) / 32;         // 1563
    const int nb64 = (NN + 63) / 64;         // 782

    k_wt<<<(INDIM * HIDIM + HIDIM * OUTDIM + 255) / 256, 256, 0, stream>>>(W1, W2, W1T, W2T);

    k_bcount<<<NBBLK, 256, 0, stream>>>(col, wcnt);
    k_bscan<<<NRANGE, 1024, 0, stream>>>(wcnt, wbase, rcur);
    k_bscatter<<<NBBLK, 256, 0, stream>>>(row, col, wbase, staged);

    k_sort<<<NRANGE, 1024, 0, stream>>>(staged, rcur, row_ptr, dinv, ssrc);

    k_gemm1<<<nb64, 256, 0, stream>>>(x, W1T, dinv, g1s, NN);
    k_agg1<<<nb32 * 4, 256, 0, stream>>>(g1s, dinv, row_ptr, ssrc, b1, hrb);
    k_gemm2<<<nb64, 256, 0, stream>>>(hrb, W2T, dinv, g2s, NN);
    k_agg2<<<nb32 * 2, 256, 0, stream>>>(g2s, dinv, row_ptr, ssrc, b2, out);
}

// Round 11
// 254.695 us; speedup vs baseline: 1.5979x; 1.5979x over previous
//
#include <hip/hip_runtime.h>

#define NN 50000
#define NE 1600000
#define INDIM 256
#define HIDIM 128
#define OUTDIM 64

#define NRANGE 64
#define RSPAN 800             // 64 * 800 = 51200 >= NN
#define ACAP 32768            // per-range staging capacity (uint records), 49 sigma margin
#define NBBLK 1563            // bucket blocks: (NE + 1023) / 1024

typedef unsigned int uint;
typedef unsigned long long ull;
typedef unsigned short ushort;
typedef __attribute__((ext_vector_type(8))) short bf16x8;
typedef __attribute__((ext_vector_type(4))) float f32x4;

__device__ __forceinline__ ushort f2bf(float f) {
    uint u = __float_as_uint(f);
    uint r = (u + 0x7FFFu + ((u >> 16) & 1u)) >> 16;   // RTNE
    return (ushort)r;
}
__device__ __forceinline__ uint pk2(float a, float b) {
    return (uint)f2bf(a) | ((uint)f2bf(b) << 16);
}
__device__ __forceinline__ float bf_lo(uint u) { return __uint_as_float(u << 16); }
__device__ __forceinline__ float bf_hi(uint u) { return __uint_as_float(u & 0xFFFF0000u); }

// ---------------- weight transpose + bf16 convert (fused) ----------------

__global__ void k_wt(const float* __restrict__ W1, const float* __restrict__ W2,
                     ushort* __restrict__ W1T, ushort* __restrict__ W2T) {
    int idx = blockIdx.x * 256 + threadIdx.x;
    if (idx < INDIM * HIDIM) {
        int k = idx / HIDIM, nn = idx % HIDIM;
        W1T[nn * INDIM + k] = f2bf(W1[idx]);
    } else {
        int j = idx - INDIM * HIDIM;
        if (j < HIDIM * OUTDIM) {
            int k = j / OUTDIM, nn = j % OUTDIM;
            W2T[nn * HIDIM + k] = f2bf(W2[j]);
        }
    }
}

// ---------------- A1: per-block range counts via LDS bins ----------------------------

__global__ void k_bcnt(const int* __restrict__ col, int* __restrict__ bcnt) {
    __shared__ int bins[NRANGE];
    int tid = threadIdx.x;
    if (tid < NRANGE) bins[tid] = 0;
    __syncthreads();
    int base = blockIdx.x * 1024 + tid;
#pragma unroll
    for (int k = 0; k < 4; k++) {
        int i = base + k * 256;
        if (i < NE) atomicAdd(&bins[col[i] / RSPAN], 1);
    }
    __syncthreads();
    if (tid < NRANGE) bcnt[tid * NBBLK + blockIdx.x] = bins[tid];
}

// ---------------- A2: per-range exclusive scan of block counts -----------------------
// 64 blocks (one per range) x 1024 threads, 2 elements/thread (2048 >= 1563).

__global__ void k_bscan(const int* __restrict__ bcnt, int* __restrict__ bbase,
                        int* __restrict__ rcur) {
    __shared__ int wsum[16];
    __shared__ int woff[16];
    int r = blockIdx.x;
    const int* src = bcnt + r * NBBLK;
    int* dst = bbase + r * NBBLK;
    int tid = threadIdx.x, lane = tid & 63, wid = tid >> 6;
    int seg = tid * 2;
    int l0 = (seg < NBBLK) ? src[seg] : 0;
    int l1 = (seg + 1 < NBBLK) ? src[seg + 1] : 0;
    int sum = l0 + l1;
    int incl = sum;
#pragma unroll
    for (int off = 1; off < 64; off <<= 1) {
        int t = __shfl_up(incl, off);
        if (lane >= off) incl += t;
    }
    if (lane == 63) wsum[wid] = incl;
    __syncthreads();
    if (wid == 0 && lane < 16) {
        int wv = wsum[lane];
        int wincl = wv;
#pragma unroll
        for (int off = 1; off < 16; off <<= 1) {
            int t = __shfl_up(wincl, off);
            if (lane >= off) wincl += t;
        }
        woff[lane] = wincl - wv;
    }
    __syncthreads();
    int run = incl - sum + woff[wid];
    if (seg < NBBLK) dst[seg] = run;
    if (seg + 1 < NBBLK) dst[seg + 1] = run + l0;
    if (tid == 1023) rcur[r] = run + sum;
}

// ---------------- A3: block-granular scatter to staged (LDS cursors) -----------------
// Segments per (block,range) avg 16 recs = 64 B: full-line, single-writer.

__global__ void k_bscat(const int* __restrict__ row, const int* __restrict__ col,
                        const int* __restrict__ bbase, uint* __restrict__ staged) {
    __shared__ int cur[NRANGE];
    int tid = threadIdx.x;
    if (tid < NRANGE) cur[tid] = bbase[tid * NBBLK + blockIdx.x];
    __syncthreads();
    int base = blockIdx.x * 1024 + tid;
#pragma unroll
    for (int k = 0; k < 4; k++) {
        int i = base + k * 256;
        if (i < NE) {
            int d = col[i], s = row[i];
            int r = d / RSPAN;
            int off = atomicAdd(&cur[r], 1);
            staged[(size_t)r * ACAP + off] = ((uint)s << 10) | (uint)(d - r * RSPAN);
        }
    }
}

// ---------------- k_sort: per-range LDS counting sort -> CSR + row_ptr + dinv --------
// 64 blocks x 1024 threads; 800 bins, ~25K records each. Zero global atomics.

__global__ void k_sort(const uint* __restrict__ staged, const int* __restrict__ rcur,
                       int* __restrict__ row_ptr, float* __restrict__ dinv,
                       ushort* __restrict__ ssrc) {
    __shared__ int bins[RSPAN];
    __shared__ int wsum[16];
    __shared__ int woff[16];
    int r = blockIdx.x;
    int tid = threadIdx.x, lane = tid & 63, wid = tid >> 6;
    int lo = r * RSPAN;
    int count = rcur[r];
    int base = 0;
    for (int rr = 0; rr < r; rr++) base += rcur[rr];
    const uint* st = staged + (size_t)r * ACAP;

    if (tid < RSPAN) bins[tid] = 0;
    __syncthreads();

    // pass 1: count
    for (int i = tid; i < count; i += 1024)
        atomicAdd(&bins[st[i] & 1023u], 1);
    __syncthreads();

    // exclusive scan of 800 bins (1 bin/thread)
    int v = (tid < RSPAN) ? bins[tid] : 0;
    int incl = v;
#pragma unroll
    for (int off = 1; off < 64; off <<= 1) {
        int t = __shfl_up(incl, off);
        if (lane >= off) incl += t;
    }
    if (lane == 63) wsum[wid] = incl;
    __syncthreads();
    if (wid == 0 && lane < 16) {
        int wv = wsum[lane];
        int wincl = wv;
#pragma unroll
        for (int off = 1; off < 16; off <<= 1) {
            int t = __shfl_up(wincl, off);
            if (lane >= off) wincl += t;
        }
        woff[lane] = wincl - wv;
    }
    __syncthreads();
    int excl = incl - v + woff[wid];
    int idx = lo + tid;
    if (tid < RSPAN && idx <= NN) {
        if (idx < NN) {
            row_ptr[idx] = base + excl;
            dinv[idx] = rsqrtf((float)(v + 1));   // +1 self loop
        } else {
            row_ptr[NN] = base + excl;            // == E (range 62, tid 400)
        }
    }
    __syncthreads();
    if (tid < RSPAN) bins[tid] = base + excl;     // global cursors for pass 2
    __syncthreads();

    // pass 2: scatter to exact CSR slots via LDS returning atomics
    for (int i = tid; i < count; i += 1024) {
        uint rec = st[i];
        int pos = atomicAdd(&bins[rec & 1023u], 1);
        ssrc[pos] = (ushort)(rec >> 10);
    }
}

// ---------------- GEMM1 (MFMA bf16): x[n][256] @ W1 -> g1s [4][NN][32] bf16 ----------

__global__ void k_gemm1(const float* __restrict__ A, const ushort* __restrict__ W1T,
                        const float* __restrict__ dinv, ushort* __restrict__ g1s, int n) {
    __shared__ ushort As[64 * 40];
    __shared__ ushort Bs[128 * 40];
    int tid = threadIdx.x;
    int w = tid >> 6, lane = tid & 63;
    int ln = lane & 15, quad = lane >> 4;
    int row0 = blockIdx.x * 64;
    int n0 = w * 32;

    f32x4 acc[4][2];
#pragma unroll
    for (int m = 0; m < 4; m++)
#pragma unroll
        for (int t = 0; t < 2; t++) acc[m][t] = (f32x4){0.f, 0.f, 0.f, 0.f};

    int ar = tid >> 2;
    int ac = (tid & 3) * 8;

    for (int k0 = 0; k0 < INDIM; k0 += 32) {
        {   // stage A: 64 rows x 32 k, f32 -> bf16
            int gr = row0 + ar;
            uint4 u = make_uint4(0, 0, 0, 0);
            if (gr < n) {
                const float* p = A + (size_t)gr * INDIM + k0 + ac;
                float4 v0 = *(const float4*)p;
                float4 v1 = *(const float4*)(p + 4);
                u.x = pk2(v0.x, v0.y); u.y = pk2(v0.z, v0.w);
                u.z = pk2(v1.x, v1.y); u.w = pk2(v1.z, v1.w);
            }
            *(uint4*)(As + ar * 40 + ac) = u;
        }
#pragma unroll
        for (int it = 0; it < 2; it++) {   // stage B: 128 rows x 32 k
            int idx = tid + it * 256;
            int bn = idx >> 2, bc = (idx & 3) * 8;
            uint4 u = *(const uint4*)(W1T + (size_t)bn * INDIM + k0 + bc);
            *(uint4*)(Bs + bn * 40 + bc) = u;
        }
        __syncthreads();

        bf16x8 af[4], bf[2];
#pragma unroll
        for (int m = 0; m < 4; m++)
            af[m] = *(const bf16x8*)(As + (m * 16 + ln) * 40 + quad * 8);
#pragma unroll
        for (int t = 0; t < 2; t++)
            bf[t] = *(const bf16x8*)(Bs + (n0 + t * 16 + ln) * 40 + quad * 8);
#pragma unroll
        for (int m = 0; m < 4; m++)
#pragma unroll
            for (int t = 0; t < 2; t++)
                acc[m][t] = __builtin_amdgcn_mfma_f32_16x16x32_bf16(af[m], bf[t], acc[m][t], 0, 0, 0);
        __syncthreads();
    }

#pragma unroll
    for (int m = 0; m < 4; m++) {
#pragma unroll
        for (int r = 0; r < 4; r++) {
            int gr = row0 + m * 16 + quad * 4 + r;
            if (gr < n) {
                float dv = dinv[gr];
#pragma unroll
                for (int t = 0; t < 2; t++) {
                    int cj = t * 16 + ln;
                    g1s[((size_t)w * NN + gr) * 32 + cj] = f2bf(acc[m][t][r] * dv);
                }
            }
        }
    }
}

// ---------------- agg1: hrb[s][d][32] = bf16(relu(dinv[d]*(sum g1[src]+g1[d]) + b1)) -

__global__ void k_agg1(const ushort* __restrict__ g1s, const float* __restrict__ dinv,
                       const int* __restrict__ row_ptr, const ushort* __restrict__ ssrc,
                       const float* __restrict__ b1, ushort* __restrict__ hrb) {
    int slice = blockIdx.x & 3;
    int dbase = (blockIdx.x >> 2) * 32;
    int wid = threadIdx.x >> 6, lane = threadIdx.x & 63;
    int grp = lane >> 3, fl = lane & 7;
    int d = dbase + wid * 8 + grp;
    if (d >= NN) return;
    const ushort* gs = g1s + (size_t)slice * NN * 32 + fl * 4;
    float a0 = 0.f, a1 = 0.f, a2 = 0.f, a3 = 0.f;
    int e0 = row_ptr[d], e1 = row_ptr[d + 1];
    int e = e0;
    for (; e + 1 < e1; e += 2) {
        int s0 = ssrc[e], s1 = ssrc[e + 1];
        uint2 u = *(const uint2*)(gs + (size_t)s0 * 32);
        uint2 v = *(const uint2*)(gs + (size_t)s1 * 32);
        a0 += bf_lo(u.x); a1 += bf_hi(u.x); a2 += bf_lo(u.y); a3 += bf_hi(u.y);
        a0 += bf_lo(v.x); a1 += bf_hi(v.x); a2 += bf_lo(v.y); a3 += bf_hi(v.y);
    }
    if (e < e1) {
        int s0 = ssrc[e];
        uint2 u = *(const uint2*)(gs + (size_t)s0 * 32);
        a0 += bf_lo(u.x); a1 += bf_hi(u.x); a2 += bf_lo(u.y); a3 += bf_hi(u.y);
    }
    uint2 ud = *(const uint2*)(gs + (size_t)d * 32);
    a0 += bf_lo(ud.x); a1 += bf_hi(ud.x); a2 += bf_lo(ud.y); a3 += bf_hi(ud.y);
    float dv = dinv[d];
    float4 bb = *(const float4*)(b1 + slice * 32 + fl * 4);
    ushort4 o;
    o.x = f2bf(fmaxf(a0 * dv + bb.x, 0.f));
    o.y = f2bf(fmaxf(a1 * dv + bb.y, 0.f));
    o.z = f2bf(fmaxf(a2 * dv + bb.z, 0.f));
    o.w = f2bf(fmaxf(a3 * dv + bb.w, 0.f));
    *(ushort4*)(hrb + ((size_t)slice * NN + d) * 32 + fl * 4) = o;
}

// ---------------- GEMM2 (MFMA bf16): hrb [4][NN][32] @ W2 -> g2s [2][NN][32] bf16 ----

__global__ void k_gemm2(const ushort* __restrict__ hrb, const ushort* __restrict__ W2T,
                        const float* __restrict__ dinv, ushort* __restrict__ g2s, int n) {
    __shared__ ushort As[64 * 40];
    __shared__ ushort Bs[64 * 40];
    int tid = threadIdx.x;
    int w = tid >> 6, lane = tid & 63;
    int ln = lane & 15, quad = lane >> 4;
    int row0 = blockIdx.x * 64;
    int n0 = w * 16;

    f32x4 acc[4];
#pragma unroll
    for (int m = 0; m < 4; m++) acc[m] = (f32x4){0.f, 0.f, 0.f, 0.f};

    int ar = tid >> 2;
    int ac = (tid & 3) * 8;

    for (int k0 = 0; k0 < HIDIM; k0 += 32) {
        int hs = k0 >> 5;
        {   // stage A
            int gr = row0 + ar;
            uint4 u = make_uint4(0, 0, 0, 0);
            if (gr < n) u = *(const uint4*)(hrb + ((size_t)hs * NN + gr) * 32 + ac);
            *(uint4*)(As + ar * 40 + ac) = u;
        }
        {   // stage B
            int bn = tid >> 2, bc = (tid & 3) * 8;
            uint4 u = *(const uint4*)(W2T + (size_t)bn * HIDIM + k0 + bc);
            *(uint4*)(Bs + bn * 40 + bc) = u;
        }
        __syncthreads();

        bf16x8 bf = *(const bf16x8*)(Bs + (n0 + ln) * 40 + quad * 8);
#pragma unroll
        for (int m = 0; m < 4; m++) {
            bf16x8 af = *(const bf16x8*)(As + (m * 16 + ln) * 40 + quad * 8);
            acc[m] = __builtin_amdgcn_mfma_f32_16x16x32_bf16(af, bf, acc[m], 0, 0, 0);
        }
        __syncthreads();
    }

    int col = n0 + ln;
    int s2 = col >> 5, cj = col & 31;
#pragma unroll
    for (int m = 0; m < 4; m++) {
#pragma unroll
        for (int r = 0; r < 4; r++) {
            int gr = row0 + m * 16 + quad * 4 + r;
            if (gr < n) {
                g2s[((size_t)s2 * NN + gr) * 32 + cj] = f2bf(acc[m][r] * dinv[gr]);
            }
        }
    }
}

// ---------------- agg2: out[d][64] = dinv[d]*(sum g2[src] + g2[d]) + b2 --------------

__global__ void k_agg2(const ushort* __restrict__ g2s, const float* __restrict__ dinv,
                       const int* __restrict__ row_ptr, const ushort* __restrict__ ssrc,
                       const float* __restrict__ b2, float* __restrict__ out) {
    int slice = blockIdx.x & 1;
    int dbase = (blockIdx.x >> 1) * 32;
    int wid = threadIdx.x >> 6, lane = threadIdx.x & 63;
    int grp = lane >> 3, fl = lane & 7;
    int d = dbase + wid * 8 + grp;
    if (d >= NN) return;
    const ushort* gs = g2s + (size_t)slice * NN * 32 + fl * 4;
    float a0 = 0.f, a1 = 0.f, a2 = 0.f, a3 = 0.f;
    int e0 = row_ptr[d], e1 = row_ptr[d + 1];
    int e = e0;
    for (; e + 1 < e1; e += 2) {
        int s0 = ssrc[e], s1 = ssrc[e + 1];
        uint2 u = *(const uint2*)(gs + (size_t)s0 * 32);
        uint2 v = *(const uint2*)(gs + (size_t)s1 * 32);
        a0 += bf_lo(u.x); a1 += bf_hi(u.x); a2 += bf_lo(u.y); a3 += bf_hi(u.y);
        a0 += bf_lo(v.x); a1 += bf_hi(v.x); a2 += bf_lo(v.y); a3 += bf_hi(v.y);
    }
    if (e < e1) {
        int s0 = ssrc[e];
        uint2 u = *(const uint2*)(gs + (size_t)s0 * 32);
        a0 += bf_lo(u.x); a1 += bf_hi(u.x); a2 += bf_lo(u.y); a3 += bf_hi(u.y);
    }
    uint2 ud = *(const uint2*)(gs + (size_t)d * 32);
    a0 += bf_lo(ud.x); a1 += bf_hi(ud.x); a2 += bf_lo(ud.y); a3 += bf_hi(ud.y);
    float dv = dinv[d];
    float4 bb = *(const float4*)(b2 + slice * 32 + fl * 4);
    float4 r;
    r.x = a0 * dv + bb.x;
    r.y = a1 * dv + bb.y;
    r.z = a2 * dv + bb.z;
    r.w = a3 * dv + bb.w;
    *(float4*)(out + (size_t)d * OUTDIM + slice * 32 + fl * 4) = r;
}

// ---------------- launch ----------------

extern "C" void kernel_launch(void* const* d_in, const int* in_sizes, int n_in,
                              void* d_out, int out_size, void* d_ws, size_t ws_size,
                              hipStream_t stream) {
    const float* x   = (const float*)d_in[0];
    const int*   ei  = (const int*)d_in[1];
    const float* W1  = (const float*)d_in[2];
    const float* b1  = (const float*)d_in[3];
    const float* W2  = (const float*)d_in[4];
    const float* b2  = (const float*)d_in[5];
    float* out = (float*)d_out;

    const int* row = ei;        // sources
    const int* col = ei + NE;   // destinations

    size_t off = 0;
    auto alloc = [&](size_t bytes) {
        void* p = (char*)d_ws + off;
        off += (bytes + 255) & ~(size_t)255;
        return p;
    };
    float*  dinv     = (float*) alloc((size_t)NN * 4);
    int*    row_ptr  = (int*)   alloc((size_t)(NN + 1) * 4);
    int*    rcur     = (int*)   alloc(NRANGE * 4);
    int*    bcnt     = (int*)   alloc((size_t)NRANGE * NBBLK * 4);   // 400 KB
    int*    bbase    = (int*)   alloc((size_t)NRANGE * NBBLK * 4);   // 400 KB
    uint*   staged   = (uint*)  alloc((size_t)NRANGE * ACAP * 4);    // 8 MB
    ushort* ssrc     = (ushort*)alloc((size_t)NE * 2);
    ushort* W1T      = (ushort*)alloc((size_t)INDIM * HIDIM * 2);
    ushort* W2T      = (ushort*)alloc((size_t)HIDIM * OUTDIM * 2);
    ushort* g1s      = (ushort*)alloc((size_t)NN * HIDIM * 2);
    ushort* hrb      = (ushort*)alloc((size_t)NN * HIDIM * 2);
    ushort* g2s      = (ushort*)alloc((size_t)NN * OUTDIM * 2);

    const int nb32 = (NN + 31) / 32;         // 1563
    const int nb64 = (NN + 63) / 64;         // 782

    k_wt<<<(INDIM * HIDIM + HIDIM * OUTDIM + 255) / 256, 256, 0, stream>>>(W1, W2, W1T, W2T);

    k_bcnt<<<NBBLK, 256, 0, stream>>>(col, bcnt);
    k_bscan<<<NRANGE, 1024, 0, stream>>>(bcnt, bbase, rcur);
    k_bscat<<<NBBLK, 256, 0, stream>>>(row, col, bbase, staged);

    k_sort<<<NRANGE, 1024, 0, stream>>>(staged, rcur, row_ptr, dinv, ssrc);

    k_gemm1<<<nb64, 256, 0, stream>>>(x, W1T, dinv, g1s, NN);
    k_agg1<<<nb32 * 4, 256, 0, stream>>>(g1s, dinv, row_ptr, ssrc, b1, hrb);
    k_gemm2<<<nb64, 256, 0, stream>>>(hrb, W2T, dinv, g2s, NN);
    k_agg2<<<nb32 * 2, 256, 0, stream>>>(g2s, dinv, row_ptr, ssrc, b2, out);
}